// Round 6
// baseline (666.251 us; speedup 1.0000x reference)
//
#include <hip/hip_runtime.h>
#include <math.h>

// Problem constants (from reference)
constexpr int Bc   = 256;      // batch
constexpr int KP1  = 4097;     // K negatives + 1
constexpr int Dc   = 128;      // feature dim
constexpr int NROW = 1000000;  // memory bank rows
constexpr float MOM = 0.5f;
constexpr float Tc  = 0.07f;

// Row-range bucketing: bucket = row >> 10 (1024 rows = 512 KB of bank each).
constexpr int NB    = (NROW + 1023) >> 10;  // 977 buckets
constexpr int CAPB  = 1280;                 // Poisson(1073), 6.3 sigma headroom
constexpr int OVCAP = 8192;                 // overflow list capacity

// ws layout: entries[NB*CAPB] (ulong) | cnt[NB] | ovcnt | ov[OVCAP]  (ints)
constexpr size_t ENT_WORDS = (size_t)NB * CAPB;      // ulongs
constexpr size_t OFF_CNT   = ENT_WORDS * 2;          // int offset
constexpr size_t OFF_OVCNT = OFF_CNT + NB;
constexpr size_t OFF_OV    = OFF_OVCNT + 1;
constexpr size_t WS_NEEDED = (OFF_OV + OVCAP) * sizeof(int);

// clang-native float4 — __builtin_nontemporal_store rejects HIP_vector_type
typedef float f4 __attribute__((ext_vector_type(4)));

// ---------------------------------------------------------------------------
__global__ __launch_bounds__(1024) void zero_kernel(int* __restrict__ p, int n) {
    const int i = threadIdx.x;
    if (i < n) p[i] = 0;
}

// ---------------------------------------------------------------------------
// Bucket-build: append each reference (row,b,k) to its row-range bucket.
__global__ __launch_bounds__(256) void build_kernel(const int* __restrict__ idx,
                                                    unsigned long long* __restrict__ entries,
                                                    int* __restrict__ cnt,
                                                    int* __restrict__ ovcnt,
                                                    int* __restrict__ ov) {
    int i = blockIdx.x * 256 + threadIdx.x;
    const int total = Bc * KP1;
    const int S = gridDim.x * 256;
    for (; i < total; i += S) {
        const int row = idx[i];
        const int bkt = row >> 10;
        const int c = atomicAdd(&cnt[bkt], 1);
        if (c < CAPB) {
            const int b = i / KP1;
            const int k = i - b * KP1;
            entries[(size_t)bkt * CAPB + c] =
                ((unsigned long long)row << 21) | (unsigned)((b << 13) | k);
        } else {
            const int o = atomicAdd(ovcnt, 1);
            if (o < OVCAP) ov[o] = i;
        }
    }
}

// ---------------------------------------------------------------------------
// Phase A: stream-copy the bank (nontemporal stores keep L3 read-populated).
__global__ __launch_bounds__(256) void copy_mem_kernel(const f4* __restrict__ src,
                                                       f4* __restrict__ dst,
                                                       int n4) {
    int i = blockIdx.x * 256 + threadIdx.x;
    const int S = gridDim.x * 256;
    for (; i + 3 * S < n4; i += 4 * S) {
        f4 a0 = src[i];
        f4 a1 = src[i + S];
        f4 a2 = src[i + 2 * S];
        f4 a3 = src[i + 3 * S];
        __builtin_nontemporal_store(a0, &dst[i]);
        __builtin_nontemporal_store(a1, &dst[i + S]);
        __builtin_nontemporal_store(a2, &dst[i + 2 * S]);
        __builtin_nontemporal_store(a3, &dst[i + 3 * S]);
    }
    for (; i < n4; i += S) __builtin_nontemporal_store(src[i], &dst[i]);
}

// ---------------------------------------------------------------------------
// Momentum scatter-update of rows y[b]; overwrites copied rows.
__global__ __launch_bounds__(64) void scatter_kernel(const float* __restrict__ memory,
                                                     const float* __restrict__ ab,
                                                     const int* __restrict__ y,
                                                     float* __restrict__ out_mem) {
    const int b = blockIdx.x;
    const int row = y[b];
    for (int b2 = b + 1; b2 < Bc; ++b2)
        if (y[b2] == row) return;  // numpy scatter: last write wins

    const int lane = threadIdx.x;  // 0..63
    float2 m = *(const float2*)(memory + (size_t)row * Dc + lane * 2);
    float2 a = *(const float2*)(ab + b * Dc + lane * 2);
    float v0 = m.x * MOM + a.x * (1.0f - MOM);
    float v1 = m.y * MOM + a.y * (1.0f - MOM);
    float s = v0 * v0 + v1 * v1;
#pragma unroll
    for (int off = 32; off; off >>= 1) s += __shfl_xor(s, off);
    const float inv = 1.0f / sqrtf(s);
    float2 o;
    o.x = v0 * inv;
    o.y = v1 * inv;
    *(float2*)(out_mem + (size_t)row * Dc + lane * 2) = o;
}

// ---------------------------------------------------------------------------
// Phase B: bucketed gather-dot. 2 blocks per bucket; 8 lanes per entry.
// Duplicate rows within a bucket are processed close in time -> L1/L2 hits;
// each block's reads are confined to a 512 KB bank window.
__global__ __launch_bounds__(256) void bucket_gather_kernel(
    const float* __restrict__ memory,
    const float* __restrict__ ab,
    const float* __restrict__ l,
    const float* __restrict__ ss,
    const int* __restrict__ cnt,
    const unsigned long long* __restrict__ entries,
    float* __restrict__ out) {
    const int bkt  = blockIdx.x >> 1;
    const int half = blockIdx.x & 1;
    int n = cnt[bkt];
    if (n > CAPB) n = CAPB;
    const unsigned long long* eb = entries + (size_t)bkt * CAPB;
    const int grp = threadIdx.x >> 3;  // 0..31
    const int sub = threadIdx.x & 7;
    const size_t plane = (size_t)Bc * KP1;
    const float invT = 1.0f / Tc;

    for (int e0 = half * 32; e0 < n; e0 += 64) {
        const int e = e0 + grp;
        if (e < n) {
            const unsigned long long v = eb[e];
            const int row = (int)(v >> 21);
            const int bq  = (int)((v >> 13) & 255);
            const int k   = (int)(v & 8191);
            const float* wrow = memory + (size_t)row * Dc;
            const float* pa = ab + bq * Dc;
            const float* pl = l  + bq * Dc;
            const float* ps = ss + bq * Dc;
            float sa = 0.f, sl = 0.f, s2 = 0.f;
#pragma unroll
            for (int it = 0; it < 4; ++it) {
                const int d = it * 32 + sub * 4;
                const float4 w  = *(const float4*)(wrow + d);
                const float4 qa = *(const float4*)(pa + d);
                const float4 ql = *(const float4*)(pl + d);
                const float4 qs = *(const float4*)(ps + d);
                sa += w.x * qa.x + w.y * qa.y + w.z * qa.z + w.w * qa.w;
                sl += w.x * ql.x + w.y * ql.y + w.z * ql.z + w.w * ql.w;
                s2 += w.x * qs.x + w.y * qs.y + w.z * qs.z + w.w * qs.w;
            }
#pragma unroll
            for (int off = 1; off < 8; off <<= 1) {
                sa += __shfl_xor(sa, off);
                sl += __shfl_xor(sl, off);
                s2 += __shfl_xor(s2, off);
            }
            if (sub == 0) {
                const size_t ob = (size_t)bq * KP1 + k;
                out[0 * plane + ob] = sa * invT;  // out_orig (ab)
                out[1 * plane + ob] = sl * invT;  // out_l
                out[2 * plane + ob] = s2 * invT;  // out_ss
            }
        }
    }
}

// ---------------------------------------------------------------------------
// Overflow entries (expected ~0): one wave per entry, full 64-lane dot.
__global__ __launch_bounds__(64) void overflow_kernel(
    const float* __restrict__ memory,
    const float* __restrict__ ab, const float* __restrict__ l,
    const float* __restrict__ ss, const int* __restrict__ idx,
    const int* __restrict__ ovcnt, const int* __restrict__ ov,
    float* __restrict__ out) {
    int n = *ovcnt;
    if (n > OVCAP) n = OVCAP;
    const int lane = threadIdx.x;
    const size_t plane = (size_t)Bc * KP1;
    const float invT = 1.0f / Tc;
    for (int t = blockIdx.x; t < n; t += gridDim.x) {
        const int i = ov[t];
        const int b = i / KP1;
        const int k = i - b * KP1;
        const int row = idx[i];
        const float2 w  = *(const float2*)(memory + (size_t)row * Dc + lane * 2);
        const float2 qa = *(const float2*)(ab + b * Dc + lane * 2);
        const float2 ql = *(const float2*)(l  + b * Dc + lane * 2);
        const float2 qs = *(const float2*)(ss + b * Dc + lane * 2);
        float sa = w.x * qa.x + w.y * qa.y;
        float sl = w.x * ql.x + w.y * ql.y;
        float s2 = w.x * qs.x + w.y * qs.y;
#pragma unroll
        for (int o = 32; o; o >>= 1) {
            sa += __shfl_xor(sa, o);
            sl += __shfl_xor(sl, o);
            s2 += __shfl_xor(s2, o);
        }
        if (lane == 0) {
            const size_t ob = (size_t)b * KP1 + k;
            out[0 * plane + ob] = sa * invT;
            out[1 * plane + ob] = sl * invT;
            out[2 * plane + ob] = s2 * invT;
        }
    }
}

// ---------------------------------------------------------------------------
// Fallback gather (round-5 proven) if ws too small.
constexpr int GY    = 32;
constexpr int NW    = GY * 4;
constexpr int KSTEP = NW * 8;
constexpr int NITER = (KP1 + KSTEP - 1) / KSTEP;

__global__ __launch_bounds__(256) void gather_dot_kernel(
    const float* __restrict__ memory,
    const float* __restrict__ ab,
    const float* __restrict__ l,
    const float* __restrict__ ss,
    const int* __restrict__ idx,
    float* __restrict__ out) {
    const int b    = blockIdx.x;
    const int lane = threadIdx.x & 63;
    const int wid  = (threadIdx.x >> 6) + (blockIdx.y << 2);
    const int g    = lane >> 3;
    const int sub  = lane & 7;

    float4 qa[4], ql[4], qs[4];
#pragma unroll
    for (int it = 0; it < 4; ++it) {
        const int d = it * 32 + sub * 4;
        qa[it] = *(const float4*)(ab + b * Dc + d);
        ql[it] = *(const float4*)(l  + b * Dc + d);
        qs[it] = *(const float4*)(ss + b * Dc + d);
    }
    const int* idxb = idx + (size_t)b * KP1;
    const size_t out_b = (size_t)b * KP1;
    const size_t plane = (size_t)Bc * KP1;
    const float invT = 1.0f / Tc;
    const int kbase = wid * 8 + g;

    int rows[NITER];
#pragma unroll
    for (int t = 0; t < NITER; ++t) {
        int k = kbase + t * KSTEP;
        rows[t] = idxb[(k < KP1) ? k : (KP1 - 1)];
    }
#pragma unroll
    for (int t = 0; t < NITER; ++t) {
        const int k = kbase + t * KSTEP;
        const float* wrow = memory + (size_t)rows[t] * Dc;
        float sa = 0.f, sl = 0.f, s2 = 0.f;
#pragma unroll
        for (int it = 0; it < 4; ++it) {
            const float4 w = *(const float4*)(wrow + it * 32 + sub * 4);
            sa += w.x * qa[it].x + w.y * qa[it].y + w.z * qa[it].z + w.w * qa[it].w;
            sl += w.x * ql[it].x + w.y * ql[it].y + w.z * ql[it].z + w.w * ql[it].w;
            s2 += w.x * qs[it].x + w.y * qs[it].y + w.z * qs[it].z + w.w * qs[it].w;
        }
#pragma unroll
        for (int off = 1; off < 8; off <<= 1) {
            sa += __shfl_xor(sa, off);
            sl += __shfl_xor(sl, off);
            s2 += __shfl_xor(s2, off);
        }
        if (sub == 0 && k < KP1) {
            out[0 * plane + out_b + k] = sa * invT;
            out[1 * plane + out_b + k] = sl * invT;
            out[2 * plane + out_b + k] = s2 * invT;
        }
    }
}

// ---------------------------------------------------------------------------
extern "C" void kernel_launch(void* const* d_in, const int* in_sizes, int n_in,
                              void* d_out, int out_size, void* d_ws, size_t ws_size,
                              hipStream_t stream) {
    const float* ab     = (const float*)d_in[0];
    const float* l      = (const float*)d_in[1];
    const float* ss     = (const float*)d_in[2];
    const float* memory = (const float*)d_in[3];
    const int*   idx    = (const int*)d_in[4];
    const int*   y      = (const int*)d_in[5];

    float* out     = (float*)d_out;
    float* out_mem = out + (size_t)3 * Bc * KP1;
    const int n4 = (NROW * Dc) / 4;  // 32M float4

    if (ws_size >= WS_NEEDED) {
        unsigned long long* entries = (unsigned long long*)d_ws;
        int* wsi   = (int*)d_ws;
        int* cnt   = wsi + OFF_CNT;
        int* ovcnt = wsi + OFF_OVCNT;
        int* ov    = wsi + OFF_OV;

        zero_kernel<<<dim3(1), dim3(1024), 0, stream>>>(cnt, NB + 1);  // cnt + ovcnt
        build_kernel<<<dim3(512), dim3(256), 0, stream>>>(idx, entries, cnt, ovcnt, ov);
        copy_mem_kernel<<<dim3(4096), dim3(256), 0, stream>>>(
            (const f4*)memory, (f4*)out_mem, n4);
        scatter_kernel<<<dim3(Bc), dim3(64), 0, stream>>>(memory, ab, y, out_mem);
        bucket_gather_kernel<<<dim3(2 * NB), dim3(256), 0, stream>>>(
            memory, ab, l, ss, cnt, entries, out);
        overflow_kernel<<<dim3(32), dim3(64), 0, stream>>>(
            memory, ab, l, ss, idx, ovcnt, ov, out);
    } else {
        copy_mem_kernel<<<dim3(4096), dim3(256), 0, stream>>>(
            (const f4*)memory, (f4*)out_mem, n4);
        scatter_kernel<<<dim3(Bc), dim3(64), 0, stream>>>(memory, ab, y, out_mem);
        gather_dot_kernel<<<dim3(Bc, GY), dim3(256), 0, stream>>>(memory, ab, l, ss, idx, out);
    }
}

// Round 7
// 305.882 us; speedup vs baseline: 2.1781x; 2.1781x over previous
//
#include <hip/hip_runtime.h>
#include <math.h>

// Problem constants (from reference)
constexpr int Bc   = 256;      // batch
constexpr int KP1  = 4097;     // K negatives + 1
constexpr int Dc   = 128;      // feature dim
constexpr int NROW = 1000000;  // memory bank rows
constexpr float MOM = 0.5f;
constexpr float Tc  = 0.07f;

// clang-native float4 — __builtin_nontemporal_store rejects HIP_vector_type
typedef float f4 __attribute__((ext_vector_type(4)));

// ---------------------------------------------------------------------------
// Phase A: stream-copy the bank. Nontemporal stores keep L3 populated with
// bank READ lines only, so the gather phase sees a warmer L3.
__global__ __launch_bounds__(256) void copy_mem_kernel(const f4* __restrict__ src,
                                                       f4* __restrict__ dst,
                                                       int n4) {
    int i = blockIdx.x * 256 + threadIdx.x;
    const int S = gridDim.x * 256;
    for (; i + 3 * S < n4; i += 4 * S) {
        f4 a0 = src[i];
        f4 a1 = src[i + S];
        f4 a2 = src[i + 2 * S];
        f4 a3 = src[i + 3 * S];
        __builtin_nontemporal_store(a0, &dst[i]);
        __builtin_nontemporal_store(a1, &dst[i + S]);
        __builtin_nontemporal_store(a2, &dst[i + 2 * S]);
        __builtin_nontemporal_store(a3, &dst[i + 3 * S]);
    }
    for (; i < n4; i += S) __builtin_nontemporal_store(src[i], &dst[i]);
}

// ---------------------------------------------------------------------------
// Momentum scatter-update of rows y[b]; overwrites copied rows.
// Last-write-wins for duplicate y (numpy scatter semantics).
__global__ __launch_bounds__(64) void scatter_kernel(const float* __restrict__ memory,
                                                     const float* __restrict__ ab,
                                                     const int* __restrict__ y,
                                                     float* __restrict__ out_mem) {
    const int b = blockIdx.x;
    const int row = y[b];
    for (int b2 = b + 1; b2 < Bc; ++b2)
        if (y[b2] == row) return;  // a later b writes this row

    const int lane = threadIdx.x;  // 0..63
    float2 m = *(const float2*)(memory + (size_t)row * Dc + lane * 2);
    float2 a = *(const float2*)(ab + b * Dc + lane * 2);
    float v0 = m.x * MOM + a.x * (1.0f - MOM);
    float v1 = m.y * MOM + a.y * (1.0f - MOM);
    float s = v0 * v0 + v1 * v1;
#pragma unroll
    for (int off = 32; off; off >>= 1) s += __shfl_xor(s, off);
    const float inv = 1.0f / sqrtf(s);
    float2 o;
    o.x = v0 * inv;
    o.y = v1 * inv;
    *(float2*)(out_mem + (size_t)row * Dc + lane * 2) = o;
}

// ---------------------------------------------------------------------------
// Phase B: gather + 3 fused dot products, FULL row prefetch.
// 8 lanes per (b,k). All NITER row indices AND all NITER*4 row float4s are
// loaded into registers before any FMA/reduce -> 20 independent 16B loads in
// flight per lane (one latency exposure instead of five); phase becomes
// DRAM-BW-bound instead of latency-bound.
constexpr int GY    = 32;            // gridDim.y
constexpr int NW    = GY * 4;        // waves per batch row b (128)
constexpr int KSTEP = NW * 8;        // k covered per iteration (1024)
constexpr int NITER = (KP1 + KSTEP - 1) / KSTEP;  // 5

__global__ __launch_bounds__(256, 2) void gather_dot_kernel(
    const float* __restrict__ memory,
    const float* __restrict__ ab,
    const float* __restrict__ l,
    const float* __restrict__ ss,
    const int* __restrict__ idx,
    float* __restrict__ out) {
    const int b    = blockIdx.x;
    const int lane = threadIdx.x & 63;
    const int wid  = (threadIdx.x >> 6) + (blockIdx.y << 2);  // 0..NW-1
    const int g    = lane >> 3;  // k-group 0..7
    const int sub  = lane & 7;   // lane within group

    const int* idxb = idx + (size_t)b * KP1;
    const size_t out_b = (size_t)b * KP1;
    const size_t plane = (size_t)Bc * KP1;
    const float invT = 1.0f / Tc;
    const int kbase = wid * 8 + g;

    // row indices upfront
    int rows[NITER];
#pragma unroll
    for (int t = 0; t < NITER; ++t) {
        int k = kbase + t * KSTEP;
        rows[t] = idxb[(k < KP1) ? k : (KP1 - 1)];
    }

    // queries (used by every iteration)
    float4 qa[4], ql[4], qs[4];
#pragma unroll
    for (int it = 0; it < 4; ++it) {
        const int d = it * 32 + sub * 4;
        qa[it] = *(const float4*)(ab + b * Dc + d);
        ql[it] = *(const float4*)(l  + b * Dc + d);
        qs[it] = *(const float4*)(ss + b * Dc + d);
    }

    // ---- issue ALL row loads before any use ----
    float4 w[NITER][4];
#pragma unroll
    for (int t = 0; t < NITER; ++t) {
        const float* wrow = memory + (size_t)rows[t] * Dc;
#pragma unroll
        for (int it = 0; it < 4; ++it)
            w[t][it] = *(const float4*)(wrow + it * 32 + sub * 4);
    }

    // ---- compute ----
#pragma unroll
    for (int t = 0; t < NITER; ++t) {
        const int k = kbase + t * KSTEP;
        float sa = 0.f, sl = 0.f, s2 = 0.f;
#pragma unroll
        for (int it = 0; it < 4; ++it) {
            const float4 v = w[t][it];
            sa += v.x * qa[it].x + v.y * qa[it].y + v.z * qa[it].z + v.w * qa[it].w;
            sl += v.x * ql[it].x + v.y * ql[it].y + v.z * ql[it].z + v.w * ql[it].w;
            s2 += v.x * qs[it].x + v.y * qs[it].y + v.z * qs[it].z + v.w * qs[it].w;
        }
#pragma unroll
        for (int off = 1; off < 8; off <<= 1) {
            sa += __shfl_xor(sa, off);
            sl += __shfl_xor(sl, off);
            s2 += __shfl_xor(s2, off);
        }
        if (sub == 0 && k < KP1) {
            out[0 * plane + out_b + k] = sa * invT;  // out_orig (ab)
            out[1 * plane + out_b + k] = sl * invT;  // out_l
            out[2 * plane + out_b + k] = s2 * invT;  // out_ss
        }
    }
}

// ---------------------------------------------------------------------------
extern "C" void kernel_launch(void* const* d_in, const int* in_sizes, int n_in,
                              void* d_out, int out_size, void* d_ws, size_t ws_size,
                              hipStream_t stream) {
    const float* ab     = (const float*)d_in[0];
    const float* l      = (const float*)d_in[1];
    const float* ss     = (const float*)d_in[2];
    const float* memory = (const float*)d_in[3];
    const int*   idx    = (const int*)d_in[4];
    const int*   y      = (const int*)d_in[5];

    float* out     = (float*)d_out;
    float* out_mem = out + (size_t)3 * Bc * KP1;

    const int n4 = (NROW * Dc) / 4;  // 32M float4
    copy_mem_kernel<<<dim3(4096), dim3(256), 0, stream>>>(
        (const f4*)memory, (f4*)out_mem, n4);
    scatter_kernel<<<dim3(Bc), dim3(64), 0, stream>>>(memory, ab, y, out_mem);
    gather_dot_kernel<<<dim3(Bc, GY), dim3(256), 0, stream>>>(memory, ab, l, ss, idx, out);
}